// Round 5
// baseline (113.295 us; speedup 1.0000x reference)
//
#include <hip/hip_runtime.h>
#include <math.h>

// ConvCapsule R5: bf16-MFMA conv AND bf16-MFMA routing.
// Block = 1 pixel, 256 threads (4 waves). Votes stored in LDS in both MFMA
// operand layouts; preact and logit-update are MFMA (block-diagonal tricks);
// only squash/softmax remain on VALU (DPP 8-lane reductions).

using short8 = __attribute__((ext_vector_type(8))) short;
using f32x4  = __attribute__((ext_vector_type(4))) float;

__device__ __forceinline__ unsigned short f2bf(float f) {
    unsigned u = __float_as_uint(f);
    return (unsigned short)((u + 0x7fffu + ((u >> 16) & 1u)) >> 16);  // RNE
}

template<int CTRL>
__device__ __forceinline__ float dpp_movf(float x) {
    return __int_as_float(__builtin_amdgcn_update_dpp(
        0, __float_as_int(x), CTRL, 0xF, 0xF, true));
}
__device__ __forceinline__ float sum8(float x) {
    x += dpp_movf<0xB1>(x);    // quad_perm [1,0,3,2]
    x += dpp_movf<0x4E>(x);    // quad_perm [2,3,0,1]
    x += dpp_movf<0x141>(x);   // row_half_mirror
    return x;
}
__device__ __forceinline__ float max8(float x) {
    x = fmaxf(x, dpp_movf<0xB1>(x));
    x = fmaxf(x, dpp_movf<0x4E>(x));
    x = fmaxf(x, dpp_movf<0x141>(x));
    return x;
}

// ---------- prep 1: W -> bf16, [s(7)][g(4)][oa(256)][j(8)], k = s*32+g*8+j ----------
__global__ __launch_bounds__(256)
void prep_w(const float* __restrict__ cw, unsigned short* __restrict__ wp) {
    const int idx = blockIdx.x * 256 + threadIdx.x;   // 57344 total
    const int j  = idx & 7;
    const int oa = (idx >> 3) & 255;
    const int g  = (idx >> 11) & 3;
    const int s  = idx >> 13;
    const int k  = s * 32 + g * 8 + j;
    wp[idx] = (k < 200) ? f2bf(cw[k * 256 + oa]) : (unsigned short)0;
}

// ---------- prep 2: x -> bf16 transposed [b][y][x][i*8+ci] ----------
__global__ __launch_bounds__(256)
void prep_x(const float* __restrict__ x, unsigned short* __restrict__ xt) {
    __shared__ unsigned short tile[32 * 256];         // [xx][plane]
    const int t = threadIdx.x;                        // plane = i*8+ci
    const int b = blockIdx.x >> 5, y = blockIdx.x & 31;
    const float* src = x + (((size_t)((b << 8) + t)) << 10) + (y << 5);
    #pragma unroll
    for (int c = 0; c < 8; ++c) {
        float4 v = *(const float4*)(src + c * 4);
        tile[(c * 4 + 0) * 256 + t] = f2bf(v.x);
        tile[(c * 4 + 1) * 256 + t] = f2bf(v.y);
        tile[(c * 4 + 2) * 256 + t] = f2bf(v.z);
        tile[(c * 4 + 3) * 256 + t] = f2bf(v.w);
    }
    __syncthreads();
    unsigned short* dst = xt + ((size_t)blockIdx.x << 13);
    #pragma unroll
    for (int c = 0; c < 4; ++c) {
        const int chunk = t + c * 256;
        *(short8*)(dst + chunk * 8) = *(const short8*)(&tile[chunk * 8]);
    }
}

// ---------- main fused kernel ----------
__global__ __launch_bounds__(256, 4)
void capsule_mfma(const unsigned short* __restrict__ xt,
                  const unsigned short* __restrict__ wp,
                  const float* __restrict__ conv_b,
                  const float* __restrict__ biases,
                  float* __restrict__ out)
{
    // LDS map (54272 B total):
    //   votes16  [32 i][264 oa] bf16 @ 0       (16896)  logit-MFMA A operand
    //   votesT16 [256 oa][40 i] bf16 @ 16896   (20480)  preact-MFMA A operand
    //   overlay @ 37376 (16896):
    //     conv:    patch [32 i][232 k] bf16 (14848)
    //     routing: logits_lds [32 i][36 o] f32 @37376 (4608)
    //              route_T [32 o][40 i] bf16 @41984 (2560)
    //              act16 [256] bf16 @44544 (512)
    //              pre_lds [256] f32 @45056 (1024)
    __shared__ __align__(16) char lds[54272];
    unsigned short* votes16  = (unsigned short*)lds;
    unsigned short* votesT16 = (unsigned short*)(lds + 16896);
    char*           patch    = lds + 37376;
    float*          logits_lds = (float*)(lds + 37376);
    unsigned short* route_T  = (unsigned short*)(lds + 41984);
    unsigned short* act16    = (unsigned short*)(lds + 44544);
    float*          pre_lds  = (float*)(lds + 45056);

    const int t   = threadIdx.x;
    const int blk = blockIdx.x;
    const int b   = blk >> 10;
    const int pix = blk & 1023;
    const int h   = pix >> 5;
    const int w   = pix & 31;

    // ---- zero-pad patch k in [200,232) ----
    if (t < 128) {
        const int i = t >> 2, c = t & 3;
        *(f32x4*)(patch + i * 464 + 400 + c * 16) = (f32x4){0.f, 0.f, 0.f, 0.f};
    }

    // ---- stage patch: unit u = (p, i); 16B per unit ----
    for (int u = t; u < 800; u += 256) {
        const int i = u & 31, p = u >> 5;
        const int ky = p / 5, kx = p - ky * 5;
        const int y = h + ky - 2, xx = w + kx - 2;
        short8 v = {0, 0, 0, 0, 0, 0, 0, 0};
        if ((unsigned)y < 32u && (unsigned)xx < 32u)
            v = *(const short8*)(xt + (((size_t)(((b << 5) + y) << 5) + xx) << 8) + i * 8);
        *(short8*)(patch + i * 464 + p * 16) = v;
    }

    // ---- conv: M=oa (A=W), N=i (B=patch), K=224 ----
    const int l  = t & 63, wv = t >> 6;
    const int lm = l & 15, lg = l >> 4;

    f32x4 acc[4][2];
    #pragma unroll
    for (int mt = 0; mt < 4; ++mt)
        #pragma unroll
        for (int ti = 0; ti < 2; ++ti)
            acc[mt][ti] = (f32x4){0.f, 0.f, 0.f, 0.f};

    __syncthreads();   // patch ready

    const unsigned short* wbase = wp + lg * 2048 + (((wv << 2) << 4) + lm) * 8;
    short8 a_cur[4], a_nxt[4];
    #pragma unroll
    for (int mt = 0; mt < 4; ++mt)
        a_cur[mt] = *(const short8*)(wbase + mt * 128);

    for (int s = 0; s < 7; ++s) {
        if (s < 6) {
            #pragma unroll
            for (int mt = 0; mt < 4; ++mt)
                a_nxt[mt] = *(const short8*)(wbase + (s + 1) * 8192 + mt * 128);
        }
        const short8 b0 = *(const short8*)(patch + lm * 464 + s * 64 + lg * 16);
        const short8 b1 = *(const short8*)(patch + (16 + lm) * 464 + s * 64 + lg * 16);
        #pragma unroll
        for (int mt = 0; mt < 4; ++mt) {
            acc[mt][0] = __builtin_amdgcn_mfma_f32_16x16x32_bf16(a_cur[mt], b0, acc[mt][0], 0, 0, 0);
            acc[mt][1] = __builtin_amdgcn_mfma_f32_16x16x32_bf16(a_cur[mt], b1, acc[mt][1], 0, 0, 0);
        }
        #pragma unroll
        for (int mt = 0; mt < 4; ++mt) a_cur[mt] = a_nxt[mt];
    }

    __syncthreads();   // all patch reads done; overlay reusable

    // ---- epilogue: fold conv_b, cvt to bf16, write BOTH vote layouts ----
    // C layout: lane (lm,lg) reg r of acc[mt][ti] = votes[oa = wv*64+mt*16+lg*4+r][i = ti*16+lm]
    #pragma unroll
    for (int mt = 0; mt < 4; ++mt) {
        const int oa0 = (wv << 6) + (mt << 4) + (lg << 2);
        const float4 cb = *(const float4*)(conv_b + oa0);
        #pragma unroll
        for (int ti = 0; ti < 2; ++ti) {
            const int i = (ti << 4) + lm;
            const unsigned short b0 = f2bf(acc[mt][ti][0] + cb.x);
            const unsigned short b1 = f2bf(acc[mt][ti][1] + cb.y);
            const unsigned short b2 = f2bf(acc[mt][ti][2] + cb.z);
            const unsigned short b3 = f2bf(acc[mt][ti][3] + cb.w);
            const unsigned long long pk =
                (unsigned long long)b0 | ((unsigned long long)b1 << 16) |
                ((unsigned long long)b2 << 32) | ((unsigned long long)b3 << 48);
            *(unsigned long long*)(votes16 + i * 264 + oa0) = pk;   // [i][oa] b64
            votesT16[(oa0 + 0) * 40 + i] = b0;                      // [oa][i]
            votesT16[(oa0 + 1) * 40 + i] = b1;
            votesT16[(oa0 + 2) * 40 + i] = b2;
            votesT16[(oa0 + 3) * 40 + i] = b3;
        }
    }

    // ---- init route_T to bf16(1/33) ----
    {
        const unsigned short r13 = f2bf(1.f / 33.f);
        const unsigned pat = (unsigned)r13 | ((unsigned)r13 << 16);
        for (int idx = t; idx < 640; idx += 256)      // 32*40 bf16 = 640 dw
            ((unsigned*)route_T)[idx] = pat;
    }
    __syncthreads();   // votes + route visible

    // ---- cache A-fragments in registers (constant across iterations) ----
    short8 pA[4];      // preact A: votesT16[(wv*64+j*16+lm)][lg*8..+8]
    #pragma unroll
    for (int j = 0; j < 4; ++j)
        pA[j] = *(const short8*)(votesT16 + ((wv << 6) + (j << 4) + lm) * 40 + (lg << 3));
    const int ib  = (wv >> 1) << 4;   // logit quadrant: i-tile base
    const int ob2 = (wv & 1) << 4;    //                 o-tile base
    short8 lA[4];      // logit A: votes16[(ib+lm)][ob2*8 + ks*32 + lg*8 ..]
    #pragma unroll
    for (int ks = 0; ks < 4; ++ks)
        lA[ks] = *(const short8*)(votes16 + (ib + lm) * 264 + (ob2 << 3) + (ks << 5) + (lg << 3));

    const int o_t = t >> 3, a_t = t & 7;
    const float bias_v = biases[t];
    const int lmT = ((wv & 1) << 3);  // preact extraction target lane base
    f32x4 lacc = {0.f, 0.f, 0.f, 0.f};
    float actv = 0.f;

    #pragma unroll
    for (int it = 0; it < 3; ++it) {
        // ---- preact MFMA: C[oa-local][o-local] = votesT x route ----
        const short8 pB = *(const short8*)(route_T + (((wv >> 1) << 4) + lm) * 40 + (lg << 3));
        #pragma unroll
        for (int j = 0; j < 4; ++j) {
            f32x4 pacc = {0.f, 0.f, 0.f, 0.f};
            pacc = __builtin_amdgcn_mfma_f32_16x16x32_bf16(pA[j], pB, pacc, 0, 0, 0);
            // diagonal o == oa>>3 lives at col lm = (wv&1)*8 + 2j + (lg>>1), rows lg*4+r
            if (lm == lmT + (j << 1) + (lg >> 1))
                *(f32x4*)(pre_lds + (wv << 6) + (j << 4) + (lg << 2)) = pacc;
        }
        __syncthreads();

        // ---- squash (8-atom DPP group) ----
        const float pre = pre_lds[t] + bias_v;
        const float ns = sum8(pre * pre);
        actv = pre * sqrtf(ns) / (1.f + ns);

        if (it == 2) break;

        // ---- act -> bf16 ----
        act16[t] = f2bf(actv);
        __syncthreads();

        // ---- logit MFMA: lacc += votes16 x act_diag (B built in registers) ----
        const short8 act8 = *(const short8*)(act16 + ((ob2 + lm) << 3));
        const short8 zz = {0, 0, 0, 0, 0, 0, 0, 0};
        #pragma unroll
        for (int ks = 0; ks < 4; ++ks) {
            const short8 bb = ((lm >> 2) == ks && (lm & 3) == lg) ? act8 : zz;
            lacc = __builtin_amdgcn_mfma_f32_16x16x32_bf16(lA[ks], bb, lacc, 0, 0, 0);
        }
        // write logits quadrant: C[i = ib+lg*4+r][o = ob2+lm]
        #pragma unroll
        for (int r = 0; r < 4; ++r)
            logits_lds[(ib + (lg << 2) + r) * 36 + ob2 + lm] = lacc[r];
        __syncthreads();

        // ---- leaky softmax over o for row i = o_t ----
        f32x4 e = *(const f32x4*)(logits_lds + o_t * 36 + (a_t << 2));
        float mx = fmaxf(fmaxf(e[0], e[1]), fmaxf(e[2], e[3]));
        mx = max8(fmaxf(mx, 0.f));            // include leak logit 0
        e[0] = __expf(e[0] - mx); e[1] = __expf(e[1] - mx);
        e[2] = __expf(e[2] - mx); e[3] = __expf(e[3] - mx);
        const float inv = 1.f / (sum8(e[0] + e[1] + e[2] + e[3]) + __expf(-mx));
        route_T[((a_t << 2) + 0) * 40 + o_t] = f2bf(e[0] * inv);
        route_T[((a_t << 2) + 1) * 40 + o_t] = f2bf(e[1] * inv);
        route_T[((a_t << 2) + 2) * 40 + o_t] = f2bf(e[2] * inv);
        route_T[((a_t << 2) + 3) * 40 + o_t] = f2bf(e[3] * inv);
        __syncthreads();
    }

    // out[b][o][h][w][a]
    out[(((size_t)(((b << 5) + o_t) << 10) + pix) << 3) + a_t] = actv;
}

extern "C" void kernel_launch(void* const* d_in, const int* in_sizes, int n_in,
                              void* d_out, int out_size, void* d_ws, size_t ws_size,
                              hipStream_t stream) {
    const float* x      = (const float*)d_in[0];
    const float* conv_w = (const float*)d_in[1];
    const float* conv_b = (const float*)d_in[2];
    const float* biases = (const float*)d_in[3];
    unsigned short* wp = (unsigned short*)d_ws;                     // 114,688 B
    unsigned short* xt = (unsigned short*)((char*)d_ws + 131072);   // 4 MB
    prep_w<<<dim3(224), dim3(256), 0, stream>>>(conv_w, wp);
    prep_x<<<dim3(256), dim3(256), 0, stream>>>(x, xt);
    capsule_mfma<<<dim3(8192), dim3(256), 0, stream>>>(xt, wp, conv_b, biases, (float*)d_out);
}